// Round 1
// baseline (1674.305 us; speedup 1.0000x reference)
//
#include <hip/hip_runtime.h>

// ---------------- zero helper ----------------
__global__ void zero_k(int* __restrict__ p, int n) {
    int i = blockIdx.x * 256 + threadIdx.x;
    if (i < n) p[i] = 0;
}

// ---------------- degree count (in-degree by col) ----------------
__global__ void count_edges_k(const int* __restrict__ col, int* __restrict__ idg, int E) {
    int e = blockIdx.x * 256 + threadIdx.x;
    if (e < E) atomicAdd(&idg[col[e]], 1);
}

// dinv[i] = rsqrt(indeg + 1 self-loop)
__global__ void dinv_k(const int* __restrict__ idg, float* __restrict__ dinv, int n) {
    int i = blockIdx.x * 256 + threadIdx.x;
    if (i < n) dinv[i] = rsqrtf((float)(idg[i] + 1));
}

// ---------------- exclusive scan (3 phases) for CSR offsets ----------------
__global__ void scan1_k(const int* __restrict__ idg, int* __restrict__ excl,
                        int* __restrict__ bsum, int n) {
    __shared__ int s[256];
    int t = threadIdx.x, i = blockIdx.x * 256 + t;
    int v = (i < n) ? idg[i] : 0;
    s[t] = v;
    __syncthreads();
    for (int off = 1; off < 256; off <<= 1) {
        int x = (t >= off) ? s[t - off] : 0;
        __syncthreads();
        s[t] += x;
        __syncthreads();
    }
    if (i < n) excl[i] = s[t] - v;
    if (t == 255) bsum[blockIdx.x] = s[255];
}

__global__ void scan2_k(const int* __restrict__ bsum, int* __restrict__ bsumx, int nb) {
    __shared__ int s[512];
    int t = threadIdx.x;
    int v = (t < nb) ? bsum[t] : 0;
    s[t] = v;
    __syncthreads();
    for (int off = 1; off < 512; off <<= 1) {
        int x = (t >= off) ? s[t - off] : 0;
        __syncthreads();
        s[t] += x;
        __syncthreads();
    }
    if (t < nb) bsumx[t] = s[t] - v;
}

__global__ void scan3_k(int* __restrict__ start, const int* __restrict__ bsumx,
                        int* __restrict__ cursor, int n) {
    int i = blockIdx.x * 256 + threadIdx.x;
    if (i < n) { start[i] += bsumx[blockIdx.x]; cursor[i] = 0; }
}

// fill CSR: edges grouped by destination (order within segment irrelevant for a sum)
__global__ void fill_k(const int* __restrict__ row, const int* __restrict__ col,
                       const int* __restrict__ start, int* __restrict__ cursor,
                       int* __restrict__ eidx, int E) {
    int e = blockIdx.x * 256 + threadIdx.x;
    if (e < E) {
        int c = col[e];
        int p = atomicAdd(&cursor[c], 1);
        eidx[start[c] + p] = row[e];
    }
}

// ---------------- fp32 GEMM: C[M,256] = A[M,K] @ W[K,256] ----------------
// 64x64 tile, 4x4 per thread, BK=16, no fp32 MFMA on CDNA4 -> vector FMA
__global__ __launch_bounds__(256) void gemm_k(const float* __restrict__ A,
                                              const float* __restrict__ W,
                                              float* __restrict__ C, int M, int K) {
    __shared__ float As[16][68];  // transposed A tile [k][m], +4 pad
    __shared__ float Bs[16][68];  // B tile [k][n], +4 pad
    int t = threadIdx.x;
    int tx = t & 15, ty = t >> 4;
    int mBase = blockIdx.x * 64;
    int nBase = blockIdx.y * 64;
    float acc[4][4] = {};
    int r = t >> 2, k4 = (t & 3) * 4;     // A staging: row r (0..63), k offset k4
    int kr = t >> 4, cc = (t & 15) * 4;   // B staging: k row kr (0..15), col cc

    for (int kt = 0; kt < K; kt += 16) {
        int gr = mBase + r;
        float4 av = make_float4(0.f, 0.f, 0.f, 0.f);
        if (gr < M) av = *(const float4*)(A + (size_t)gr * K + kt + k4);
        float4 bv = *(const float4*)(W + (size_t)(kt + kr) * 256 + nBase + cc);
        As[k4 + 0][r] = av.x; As[k4 + 1][r] = av.y;
        As[k4 + 2][r] = av.z; As[k4 + 3][r] = av.w;
        *(float4*)&Bs[kr][cc] = bv;
        __syncthreads();
#pragma unroll
        for (int kk = 0; kk < 16; ++kk) {
            float4 a = *(const float4*)&As[kk][ty * 4];
            float4 b = *(const float4*)&Bs[kk][tx * 4];
            float aa[4] = {a.x, a.y, a.z, a.w};
            float bb[4] = {b.x, b.y, b.z, b.w};
#pragma unroll
            for (int i2 = 0; i2 < 4; ++i2)
#pragma unroll
                for (int j2 = 0; j2 < 4; ++j2)
                    acc[i2][j2] = fmaf(aa[i2], bb[j2], acc[i2][j2]);
        }
        __syncthreads();
    }
#pragma unroll
    for (int i2 = 0; i2 < 4; ++i2) {
        int gr = mBase + ty * 4 + i2;
        if (gr < M) {
            float4 o = make_float4(acc[i2][0], acc[i2][1], acc[i2][2], acc[i2][3]);
            *(float4*)(C + (size_t)gr * 256 + nBase + tx * 4) = o;
        }
    }
}

// ---------------- GCN aggregate: out[i] = relu(b + sum_j norm*h[r_j]) ----------------
// one wave (64 lanes) per node, float4 per lane covers 256 dims
__global__ __launch_bounds__(256) void agg_k(const float* __restrict__ h,
                                             float* __restrict__ out,
                                             const float* __restrict__ dinv,
                                             const int* __restrict__ start,
                                             const int* __restrict__ idg,
                                             const int* __restrict__ eidx,
                                             const float* __restrict__ bias, int n) {
    int w = threadIdx.x >> 6, lane = threadIdx.x & 63;
    int i = blockIdx.x * 4 + w;
    if (i >= n) return;
    float di = dinv[i];
    float4 acc = ((const float4*)(h + (size_t)i * 256))[lane];  // self-loop
    float sw = di * di;
    acc.x *= sw; acc.y *= sw; acc.z *= sw; acc.w *= sw;
    int s0 = start[i], cnt = idg[i];
    for (int j = 0; j < cnt; ++j) {
        int rr = eidx[s0 + j];
        float wg = dinv[rr] * di;
        float4 hv = ((const float4*)(h + (size_t)rr * 256))[lane];
        acc.x = fmaf(hv.x, wg, acc.x);
        acc.y = fmaf(hv.y, wg, acc.y);
        acc.z = fmaf(hv.z, wg, acc.z);
        acc.w = fmaf(hv.w, wg, acc.w);
    }
    float4 bv = ((const float4*)bias)[lane];
    acc.x = fmaxf(acc.x + bv.x, 0.f);
    acc.y = fmaxf(acc.y + bv.y, 0.f);
    acc.z = fmaxf(acc.z + bv.z, 0.f);
    acc.w = fmaxf(acc.w + bv.w, 0.f);
    ((float4*)(out + (size_t)i * 256))[lane] = acc;
}

// ---------------- mean pool ----------------
__global__ void cnt_k(const int* __restrict__ batch, float* __restrict__ cntb, int n) {
    int i = blockIdx.x * 256 + threadIdx.x;
    if (i < n) atomicAdd(&cntb[batch[i]], 1.0f);
}

// batch is sorted: per-block running sum per dim, flush on graph change
__global__ void pool_k(const float* __restrict__ h, const int* __restrict__ batch,
                       float* __restrict__ outsum, int n) {
    int d = threadIdx.x;  // 0..255
    int n0 = blockIdx.x * 128;
    int n1 = min(n0 + 128, n);
    int gcur = -1;
    float sum = 0.f;
    for (int nn = n0; nn < n1; ++nn) {
        int g = batch[nn];
        float v = h[(size_t)nn * 256 + d];
        if (g != gcur) {
            if (gcur >= 0) atomicAdd(&outsum[gcur * 256 + d], sum);
            gcur = g;
            sum = v;
        } else {
            sum += v;
        }
    }
    if (gcur >= 0) atomicAdd(&outsum[gcur * 256 + d], sum);
}

__global__ void final_k(float* __restrict__ out, const float* __restrict__ cntb) {
    int g = blockIdx.x, d = threadIdx.x;
    out[g * 256 + d] /= fmaxf(cntb[g], 1.0f);
}

extern "C" void kernel_launch(void* const* d_in, const int* in_sizes, int n_in,
                              void* d_out, int out_size, void* d_ws, size_t ws_size,
                              hipStream_t stream) {
    const float* x  = (const float*)d_in[0];
    const int*   ei = (const int*)d_in[1];
    const int*   batch = (const int*)d_in[2];
    const float* W1 = (const float*)d_in[3];
    const float* b1 = (const float*)d_in[4];
    const float* W2 = (const float*)d_in[5];
    const float* b2 = (const float*)d_in[6];
    float* out = (float*)d_out;

    const int N  = in_sizes[2];          // 100000
    const int E  = in_sizes[1] / 2;      // 1600000
    const int K1 = in_sizes[0] / N;      // 128
    const int* row = ei;
    const int* col = ei + E;

    // workspace carve-out (all recomputed each call; ws is poisoned between calls)
    char* p = (char*)d_ws;
    auto alloc = [&](size_t bytes) {
        char* q = p;
        p += (bytes + 255) & ~(size_t)255;
        return q;
    };
    int*   idg    = (int*)alloc((size_t)N * 4);
    int*   startv = (int*)alloc((size_t)N * 4);
    int*   cursor = (int*)alloc((size_t)N * 4);
    int*   bsum   = (int*)alloc(2048);
    int*   bsumx  = (int*)alloc(2048);
    int*   eidx   = (int*)alloc((size_t)E * 4);
    float* dinv   = (float*)alloc((size_t)N * 4);
    float* cntb   = (float*)alloc(256 * 4);
    float* hA     = (float*)alloc((size_t)N * 256 * 4);
    float* hB     = (float*)alloc((size_t)N * 256 * 4);

    const int nb  = (N + 255) / 256;   // 391 (fits scan2's 512 threads)
    const int ebl = (E + 255) / 256;

    // zero init (kernels: keep graph capture trivially safe)
    zero_k<<<nb, 256, 0, stream>>>(idg, N);
    zero_k<<<1, 256, 0, stream>>>((int*)cntb, 64);
    zero_k<<<(out_size + 255) / 256, 256, 0, stream>>>((int*)out, out_size);

    // GCN normalization + CSR build (per-call, edge structure from inputs)
    count_edges_k<<<ebl, 256, 0, stream>>>(col, idg, E);
    dinv_k<<<nb, 256, 0, stream>>>(idg, dinv, N);
    scan1_k<<<nb, 256, 0, stream>>>(idg, startv, bsum, N);
    scan2_k<<<1, 512, 0, stream>>>(bsum, bsumx, nb);
    scan3_k<<<nb, 256, 0, stream>>>(startv, bsumx, cursor, N);
    fill_k<<<ebl, 256, 0, stream>>>(row, col, startv, cursor, eidx, E);

    // layer 1: x @ W1 -> hA ; aggregate+bias+relu -> hB
    dim3 g1((N + 63) / 64, 4);
    gemm_k<<<g1, 256, 0, stream>>>(x, W1, hA, N, K1);
    agg_k<<<(N + 3) / 4, 256, 0, stream>>>(hA, hB, dinv, startv, idg, eidx, b1, N);

    // layer 2: hB @ W2 -> hA ; aggregate+bias+relu -> hB
    gemm_k<<<g1, 256, 0, stream>>>(hB, W2, hA, N, 256);
    agg_k<<<(N + 3) / 4, 256, 0, stream>>>(hA, hB, dinv, startv, idg, eidx, b2, N);

    // global mean pool
    cnt_k<<<nb, 256, 0, stream>>>(batch, cntb, N);
    pool_k<<<(N + 127) / 128, 256, 0, stream>>>(hB, batch, out, N);
    final_k<<<64, 256, 0, stream>>>(out, cntb);
}

// Round 2
// 1051.304 us; speedup vs baseline: 1.5926x; 1.5926x over previous
//
#include <hip/hip_runtime.h>

// ---------------- zero helper ----------------
__global__ void zero_k(int* __restrict__ p, int n) {
    int i = blockIdx.x * 256 + threadIdx.x;
    if (i < n) p[i] = 0;
}

// ---------------- degree count (in-degree by col) ----------------
__global__ void count_edges_k(const int* __restrict__ col, int* __restrict__ idg, int E) {
    int e = blockIdx.x * 256 + threadIdx.x;
    if (e < E) atomicAdd(&idg[col[e]], 1);
}

// dinv[i] = rsqrt(indeg + 1 self-loop)
__global__ void dinv_k(const int* __restrict__ idg, float* __restrict__ dinv, int n) {
    int i = blockIdx.x * 256 + threadIdx.x;
    if (i < n) dinv[i] = rsqrtf((float)(idg[i] + 1));
}

// ---------------- exclusive scan (3 phases) for CSR offsets ----------------
__global__ void scan1_k(const int* __restrict__ idg, int* __restrict__ excl,
                        int* __restrict__ bsum, int n) {
    __shared__ int s[256];
    int t = threadIdx.x, i = blockIdx.x * 256 + t;
    int v = (i < n) ? idg[i] : 0;
    s[t] = v;
    __syncthreads();
    for (int off = 1; off < 256; off <<= 1) {
        int x = (t >= off) ? s[t - off] : 0;
        __syncthreads();
        s[t] += x;
        __syncthreads();
    }
    if (i < n) excl[i] = s[t] - v;
    if (t == 255) bsum[blockIdx.x] = s[255];
}

__global__ void scan2_k(const int* __restrict__ bsum, int* __restrict__ bsumx, int nb) {
    __shared__ int s[512];
    int t = threadIdx.x;
    int v = (t < nb) ? bsum[t] : 0;
    s[t] = v;
    __syncthreads();
    for (int off = 1; off < 512; off <<= 1) {
        int x = (t >= off) ? s[t - off] : 0;
        __syncthreads();
        s[t] += x;
        __syncthreads();
    }
    if (t < nb) bsumx[t] = s[t] - v;
}

__global__ void scan3_k(int* __restrict__ start, const int* __restrict__ bsumx,
                        int* __restrict__ cursor, int n) {
    int i = blockIdx.x * 256 + threadIdx.x;
    if (i < n) { start[i] += bsumx[blockIdx.x]; cursor[i] = 0; }
}

// fill CSR: edges grouped by destination (order within segment irrelevant for a sum)
__global__ void fill_k(const int* __restrict__ row, const int* __restrict__ col,
                       const int* __restrict__ start, int* __restrict__ cursor,
                       int* __restrict__ eidx, int E) {
    int e = blockIdx.x * 256 + threadIdx.x;
    if (e < E) {
        int c = col[e];
        int p = atomicAdd(&cursor[c], 1);
        eidx[start[c] + p] = row[e];
    }
}

// ---------------- fp32 GEMM: C[M,256] = A[M,K] @ W[K,256] ----------------
// 64x64 tile, 4x4 per thread, BK=16, no fp32 MFMA on CDNA4 -> vector FMA
__global__ __launch_bounds__(256) void gemm_k(const float* __restrict__ A,
                                              const float* __restrict__ W,
                                              float* __restrict__ C, int M, int K) {
    __shared__ float As[16][68];  // transposed A tile [k][m], +4 pad
    __shared__ float Bs[16][68];  // B tile [k][n], +4 pad
    int t = threadIdx.x;
    int tx = t & 15, ty = t >> 4;
    int mBase = blockIdx.x * 64;
    int nBase = blockIdx.y * 64;
    float acc[4][4] = {};
    int r = t >> 2, k4 = (t & 3) * 4;     // A staging: row r (0..63), k offset k4
    int kr = t >> 4, cc = (t & 15) * 4;   // B staging: k row kr (0..15), col cc

    for (int kt = 0; kt < K; kt += 16) {
        int gr = mBase + r;
        float4 av = make_float4(0.f, 0.f, 0.f, 0.f);
        if (gr < M) av = *(const float4*)(A + (size_t)gr * K + kt + k4);
        float4 bv = *(const float4*)(W + (size_t)(kt + kr) * 256 + nBase + cc);
        As[k4 + 0][r] = av.x; As[k4 + 1][r] = av.y;
        As[k4 + 2][r] = av.z; As[k4 + 3][r] = av.w;
        *(float4*)&Bs[kr][cc] = bv;
        __syncthreads();
#pragma unroll
        for (int kk = 0; kk < 16; ++kk) {
            float4 a = *(const float4*)&As[kk][ty * 4];
            float4 b = *(const float4*)&Bs[kk][tx * 4];
            float aa[4] = {a.x, a.y, a.z, a.w};
            float bb[4] = {b.x, b.y, b.z, b.w};
#pragma unroll
            for (int i2 = 0; i2 < 4; ++i2)
#pragma unroll
                for (int j2 = 0; j2 < 4; ++j2)
                    acc[i2][j2] = fmaf(aa[i2], bb[j2], acc[i2][j2]);
        }
        __syncthreads();
    }
#pragma unroll
    for (int i2 = 0; i2 < 4; ++i2) {
        int gr = mBase + ty * 4 + i2;
        if (gr < M) {
            float4 o = make_float4(acc[i2][0], acc[i2][1], acc[i2][2], acc[i2][3]);
            *(float4*)(C + (size_t)gr * 256 + nBase + tx * 4) = o;
        }
    }
}

// ---------------- GCN aggregate: out[i] = relu(b + sum_j norm*h[r_j]) ----------------
// one wave (64 lanes) per node, float4 per lane covers 256 dims
__global__ __launch_bounds__(256) void agg_k(const float* __restrict__ h,
                                             float* __restrict__ out,
                                             const float* __restrict__ dinv,
                                             const int* __restrict__ start,
                                             const int* __restrict__ idg,
                                             const int* __restrict__ eidx,
                                             const float* __restrict__ bias, int n) {
    int w = threadIdx.x >> 6, lane = threadIdx.x & 63;
    int i = blockIdx.x * 4 + w;
    if (i >= n) return;
    float di = dinv[i];
    float4 acc = ((const float4*)(h + (size_t)i * 256))[lane];  // self-loop
    float sw = di * di;
    acc.x *= sw; acc.y *= sw; acc.z *= sw; acc.w *= sw;
    int s0 = start[i], cnt = idg[i];
    for (int j = 0; j < cnt; ++j) {
        int rr = eidx[s0 + j];
        float wg = dinv[rr] * di;
        float4 hv = ((const float4*)(h + (size_t)rr * 256))[lane];
        acc.x = fmaf(hv.x, wg, acc.x);
        acc.y = fmaf(hv.y, wg, acc.y);
        acc.z = fmaf(hv.z, wg, acc.z);
        acc.w = fmaf(hv.w, wg, acc.w);
    }
    float4 bv = ((const float4*)bias)[lane];
    acc.x = fmaxf(acc.x + bv.x, 0.f);
    acc.y = fmaxf(acc.y + bv.y, 0.f);
    acc.z = fmaxf(acc.z + bv.z, 0.f);
    acc.w = fmaxf(acc.w + bv.w, 0.f);
    ((float4*)(out + (size_t)i * 256))[lane] = acc;
}

// ---------------- mean pool ----------------
// batch sorted -> graph counts are segment boundaries; 64 threads binary-search.
// Replaces the 631us atomic histogram (100K same-address float atomics).
__global__ void cnt_bounds_k(const int* __restrict__ batch, float* __restrict__ cntb,
                             int n) {
    int g = threadIdx.x;  // 0..63
    int lo = 0, hi = n;
    while (lo < hi) { int mid = (lo + hi) >> 1; if (batch[mid] < g) lo = mid + 1; else hi = mid; }
    int s = lo;
    lo = 0; hi = n;
    int g1 = g + 1;
    while (lo < hi) { int mid = (lo + hi) >> 1; if (batch[mid] < g1) lo = mid + 1; else hi = mid; }
    cntb[g] = (float)(lo - s);
}

// batch is sorted: per-block running sum per dim, flush on graph change
__global__ void pool_k(const float* __restrict__ h, const int* __restrict__ batch,
                       float* __restrict__ outsum, int n) {
    int d = threadIdx.x;  // 0..255
    int n0 = blockIdx.x * 128;
    int n1 = min(n0 + 128, n);
    int gcur = -1;
    float sum = 0.f;
    for (int nn = n0; nn < n1; ++nn) {
        int g = batch[nn];
        float v = h[(size_t)nn * 256 + d];
        if (g != gcur) {
            if (gcur >= 0) atomicAdd(&outsum[gcur * 256 + d], sum);
            gcur = g;
            sum = v;
        } else {
            sum += v;
        }
    }
    if (gcur >= 0) atomicAdd(&outsum[gcur * 256 + d], sum);
}

__global__ void final_k(float* __restrict__ out, const float* __restrict__ cntb) {
    int g = blockIdx.x, d = threadIdx.x;
    out[g * 256 + d] /= fmaxf(cntb[g], 1.0f);
}

extern "C" void kernel_launch(void* const* d_in, const int* in_sizes, int n_in,
                              void* d_out, int out_size, void* d_ws, size_t ws_size,
                              hipStream_t stream) {
    const float* x  = (const float*)d_in[0];
    const int*   ei = (const int*)d_in[1];
    const int*   batch = (const int*)d_in[2];
    const float* W1 = (const float*)d_in[3];
    const float* b1 = (const float*)d_in[4];
    const float* W2 = (const float*)d_in[5];
    const float* b2 = (const float*)d_in[6];
    float* out = (float*)d_out;

    const int N  = in_sizes[2];          // 100000
    const int E  = in_sizes[1] / 2;      // 1600000
    const int K1 = in_sizes[0] / N;      // 128
    const int* row = ei;
    const int* col = ei + E;

    // workspace carve-out (all recomputed each call; ws is poisoned between calls)
    char* p = (char*)d_ws;
    auto alloc = [&](size_t bytes) {
        char* q = p;
        p += (bytes + 255) & ~(size_t)255;
        return q;
    };
    int*   idg    = (int*)alloc((size_t)N * 4);
    int*   startv = (int*)alloc((size_t)N * 4);
    int*   cursor = (int*)alloc((size_t)N * 4);
    int*   bsum   = (int*)alloc(2048);
    int*   bsumx  = (int*)alloc(2048);
    int*   eidx   = (int*)alloc((size_t)E * 4);
    float* dinv   = (float*)alloc((size_t)N * 4);
    float* cntb   = (float*)alloc(256 * 4);
    float* hA     = (float*)alloc((size_t)N * 256 * 4);
    float* hB     = (float*)alloc((size_t)N * 256 * 4);

    const int nb  = (N + 255) / 256;   // 391 (fits scan2's 512 threads)
    const int ebl = (E + 255) / 256;

    // zero init (kernels: keep graph capture trivially safe)
    zero_k<<<nb, 256, 0, stream>>>(idg, N);
    zero_k<<<(out_size + 255) / 256, 256, 0, stream>>>((int*)out, out_size);

    // GCN normalization + CSR build (per-call, edge structure from inputs)
    count_edges_k<<<ebl, 256, 0, stream>>>(col, idg, E);
    dinv_k<<<nb, 256, 0, stream>>>(idg, dinv, N);
    scan1_k<<<nb, 256, 0, stream>>>(idg, startv, bsum, N);
    scan2_k<<<1, 512, 0, stream>>>(bsum, bsumx, nb);
    scan3_k<<<nb, 256, 0, stream>>>(startv, bsumx, cursor, N);
    fill_k<<<ebl, 256, 0, stream>>>(row, col, startv, cursor, eidx, E);

    // layer 1: x @ W1 -> hA ; aggregate+bias+relu -> hB
    dim3 g1((N + 63) / 64, 4);
    gemm_k<<<g1, 256, 0, stream>>>(x, W1, hA, N, K1);
    agg_k<<<(N + 3) / 4, 256, 0, stream>>>(hA, hB, dinv, startv, idg, eidx, b1, N);

    // layer 2: hB @ W2 -> hA ; aggregate+bias+relu -> hB
    gemm_k<<<g1, 256, 0, stream>>>(hB, W2, hA, N, 256);
    agg_k<<<(N + 3) / 4, 256, 0, stream>>>(hA, hB, dinv, startv, idg, eidx, b2, N);

    // global mean pool (batch sorted -> binary-search counts, no atomics)
    cnt_bounds_k<<<1, 64, 0, stream>>>(batch, cntb, N);
    pool_k<<<(N + 127) / 128, 256, 0, stream>>>(hB, batch, out, N);
    final_k<<<64, 256, 0, stream>>>(out, cntb);
}

// Round 3
// 657.109 us; speedup vs baseline: 2.5480x; 1.5999x over previous
//
#include <hip/hip_runtime.h>

typedef __attribute__((ext_vector_type(8))) short short8;    // 8 bf16 (4 VGPRs)
typedef __attribute__((ext_vector_type(4))) float float4v;   // 4 fp32 acc

__device__ __forceinline__ ushort f2bf(float f) {
    uint u = __float_as_uint(f);
    u += 0x7fffu + ((u >> 16) & 1u);   // round-to-nearest-even
    return (ushort)(u >> 16);
}
__device__ __forceinline__ float bf2f(ushort h) {
    return __uint_as_float((uint)h << 16);
}

// ---------------- zero helper ----------------
__global__ void zero_k(int* __restrict__ p, int n) {
    int i = blockIdx.x * 256 + threadIdx.x;
    if (i < n) p[i] = 0;
}

// ---------------- degree count (in-degree by col) ----------------
__global__ void count_edges_k(const int* __restrict__ col, int* __restrict__ idg, int E) {
    int e = blockIdx.x * 256 + threadIdx.x;
    if (e < E) atomicAdd(&idg[col[e]], 1);
}

__global__ void dinv_k(const int* __restrict__ idg, float* __restrict__ dinv, int n) {
    int i = blockIdx.x * 256 + threadIdx.x;
    if (i < n) dinv[i] = rsqrtf((float)(idg[i] + 1));
}

// ---------------- exclusive scan (3 phases) for CSR offsets ----------------
__global__ void scan1_k(const int* __restrict__ idg, int* __restrict__ excl,
                        int* __restrict__ bsum, int n) {
    __shared__ int s[256];
    int t = threadIdx.x, i = blockIdx.x * 256 + t;
    int v = (i < n) ? idg[i] : 0;
    s[t] = v;
    __syncthreads();
    for (int off = 1; off < 256; off <<= 1) {
        int x = (t >= off) ? s[t - off] : 0;
        __syncthreads();
        s[t] += x;
        __syncthreads();
    }
    if (i < n) excl[i] = s[t] - v;
    if (t == 255) bsum[blockIdx.x] = s[255];
}

__global__ void scan2_k(const int* __restrict__ bsum, int* __restrict__ bsumx, int nb) {
    __shared__ int s[512];
    int t = threadIdx.x;
    int v = (t < nb) ? bsum[t] : 0;
    s[t] = v;
    __syncthreads();
    for (int off = 1; off < 512; off <<= 1) {
        int x = (t >= off) ? s[t - off] : 0;
        __syncthreads();
        s[t] += x;
        __syncthreads();
    }
    if (t < nb) bsumx[t] = s[t] - v;
}

__global__ void scan3_k(int* __restrict__ start, const int* __restrict__ bsumx,
                        int* __restrict__ cursor, int n) {
    int i = blockIdx.x * 256 + threadIdx.x;
    if (i < n) { start[i] += bsumx[blockIdx.x]; cursor[i] = 0; }
}

__global__ void fill_k(const int* __restrict__ row, const int* __restrict__ col,
                       const int* __restrict__ start, int* __restrict__ cursor,
                       int* __restrict__ eidx, int E) {
    int e = blockIdx.x * 256 + threadIdx.x;
    if (e < E) {
        int c = col[e];
        int p = atomicAdd(&cursor[c], 1);
        eidx[start[c] + p] = row[e];
    }
}

// ---------------- pack W[K x 256] fp32 -> bf16 MFMA B-fragment order ----------------
// element (((nt*S + s)*64 + lane)*8 + j) = W[32s + (lane>>4)*8 + j][16nt + (lane&15)]
__global__ void packW_k(const float* __restrict__ W, ushort* __restrict__ Wp, int K) {
    int idx = blockIdx.x * 256 + threadIdx.x;
    int S = K / 32;
    int j = idx & 7;
    int lane = (idx >> 3) & 63;
    int s = (idx >> 9) % S;
    int nt = (idx >> 9) / S;
    int k = 32 * s + (lane >> 4) * 8 + j;
    int c = nt * 16 + (lane & 15);
    Wp[idx] = f2bf(W[k * 256 + c]);
}

// ---------------- agg1: aggX[i] = sum_norm x[rows]  (128 dims fp32 -> bf16) ----------------
__global__ __launch_bounds__(256) void agg1_k(const float* __restrict__ x,
                                              ushort* __restrict__ out,
                                              const float* __restrict__ dinv,
                                              const int* __restrict__ start,
                                              const int* __restrict__ idg,
                                              const int* __restrict__ eidx, int n) {
    int w = threadIdx.x >> 6, lane = threadIdx.x & 63;
    int i = blockIdx.x * 4 + w;
    if (i >= n) return;
    float di = dinv[i];
    float2 self = ((const float2*)(x + (size_t)i * 128))[lane];
    float sw = di * di;
    float ax = self.x * sw, ay = self.y * sw;
    int s0 = start[i], cnt = idg[i];
    int j = 0;
    for (; j + 1 < cnt; j += 2) {
        int r0 = eidx[s0 + j], r1 = eidx[s0 + j + 1];
        float w0 = dinv[r0] * di, w1 = dinv[r1] * di;
        float2 h0 = ((const float2*)(x + (size_t)r0 * 128))[lane];
        float2 h1 = ((const float2*)(x + (size_t)r1 * 128))[lane];
        ax = fmaf(h0.x, w0, ax); ay = fmaf(h0.y, w0, ay);
        ax = fmaf(h1.x, w1, ax); ay = fmaf(h1.y, w1, ay);
    }
    if (j < cnt) {
        int r0 = eidx[s0 + j];
        float w0 = dinv[r0] * di;
        float2 h0 = ((const float2*)(x + (size_t)r0 * 128))[lane];
        ax = fmaf(h0.x, w0, ax); ay = fmaf(h0.y, w0, ay);
    }
    ushort2 o; o.x = f2bf(ax); o.y = f2bf(ay);
    ((ushort2*)(out + (size_t)i * 128))[lane] = o;
}

// ---------------- agg2: aggH[i] = sum_norm h[rows]  (256 dims bf16 -> bf16) ----------------
__global__ __launch_bounds__(256) void agg2_k(const ushort* __restrict__ h,
                                              ushort* __restrict__ out,
                                              const float* __restrict__ dinv,
                                              const int* __restrict__ start,
                                              const int* __restrict__ idg,
                                              const int* __restrict__ eidx, int n) {
    int w = threadIdx.x >> 6, lane = threadIdx.x & 63;
    int i = blockIdx.x * 4 + w;
    if (i >= n) return;
    float di = dinv[i];
    ushort4 sv = ((const ushort4*)(h + (size_t)i * 256))[lane];
    float sw = di * di;
    float a0 = bf2f(sv.x) * sw, a1 = bf2f(sv.y) * sw;
    float a2 = bf2f(sv.z) * sw, a3 = bf2f(sv.w) * sw;
    int s0 = start[i], cnt = idg[i];
    int j = 0;
    for (; j + 1 < cnt; j += 2) {
        int r0 = eidx[s0 + j], r1 = eidx[s0 + j + 1];
        float w0 = dinv[r0] * di, w1 = dinv[r1] * di;
        ushort4 v0 = ((const ushort4*)(h + (size_t)r0 * 256))[lane];
        ushort4 v1 = ((const ushort4*)(h + (size_t)r1 * 256))[lane];
        a0 = fmaf(bf2f(v0.x), w0, a0); a1 = fmaf(bf2f(v0.y), w0, a1);
        a2 = fmaf(bf2f(v0.z), w0, a2); a3 = fmaf(bf2f(v0.w), w0, a3);
        a0 = fmaf(bf2f(v1.x), w1, a0); a1 = fmaf(bf2f(v1.y), w1, a1);
        a2 = fmaf(bf2f(v1.z), w1, a2); a3 = fmaf(bf2f(v1.w), w1, a3);
    }
    if (j < cnt) {
        int r0 = eidx[s0 + j];
        float w0 = dinv[r0] * di;
        ushort4 v0 = ((const ushort4*)(h + (size_t)r0 * 256))[lane];
        a0 = fmaf(bf2f(v0.x), w0, a0); a1 = fmaf(bf2f(v0.y), w0, a1);
        a2 = fmaf(bf2f(v0.z), w0, a2); a3 = fmaf(bf2f(v0.w), w0, a3);
    }
    ushort4 o;
    o.x = f2bf(a0); o.y = f2bf(a1); o.z = f2bf(a2); o.w = f2bf(a3);
    ((ushort4*)(out + (size_t)i * 256))[lane] = o;
}

// ---------------- MFMA bf16 GEMM: C[M,256] = relu(A[M,K] @ W + b), bf16 out ----------------
// A-frag: lane holds A[m=lane&15][k=quad*8+j]; B from packed Wp; C/D: col=lane&15,
// row=quad*4+reg (doc-verified gfx950 16x16x32 layouts). 4 waves x 16 rows = 64-row tile,
// blockIdx.y = 64-col group.
template <int K>
__global__ __launch_bounds__(256) void gemm_mfma_k(const ushort* __restrict__ A,
                                                   const ushort* __restrict__ Wp,
                                                   const float* __restrict__ bias,
                                                   ushort* __restrict__ C, int M) {
    constexpr int S = K / 32;
    int tid = threadIdx.x, wv = tid >> 6, lane = tid & 63;
    int quad = lane >> 4, l15 = lane & 15;
    int rowBase = blockIdx.x * 64 + wv * 16;
    int arow = rowBase + l15; if (arow > M - 1) arow = M - 1;   // clamp (stores guarded)
    const ushort* abase = A + (size_t)arow * K + quad * 8;
    short8 af[S];
#pragma unroll
    for (int s = 0; s < S; ++s) af[s] = *(const short8*)(abase + 32 * s);

    int ntg0 = blockIdx.y * 4;
    float4v acc[4];
#pragma unroll
    for (int nt = 0; nt < 4; ++nt) {
        float4v a = {0.f, 0.f, 0.f, 0.f};
        const ushort* wb = Wp + ((size_t)(ntg0 + nt) * S * 64 + lane) * 8;
#pragma unroll
        for (int s = 0; s < S; ++s) {
            short8 bf = *(const short8*)(wb + (size_t)s * 64 * 8);
            a = __builtin_amdgcn_mfma_f32_16x16x32_bf16(af[s], bf, a, 0, 0, 0);
        }
        acc[nt] = a;
    }
#pragma unroll
    for (int nt = 0; nt < 4; ++nt) {
        int col = blockIdx.y * 64 + nt * 16 + l15;
        float b = bias[col];
#pragma unroll
        for (int r = 0; r < 4; ++r) {
            int row = rowBase + quad * 4 + r;
            if (row < M) {
                float v = fmaxf(acc[nt][r] + b, 0.f);
                C[(size_t)row * 256 + col] = f2bf(v);
            }
        }
    }
}

// ---------------- mean pool ----------------
__global__ void cnt_bounds_k(const int* __restrict__ batch, float* __restrict__ cntb,
                             int n) {
    int g = threadIdx.x;  // 0..63
    int lo = 0, hi = n;
    while (lo < hi) { int mid = (lo + hi) >> 1; if (batch[mid] < g) lo = mid + 1; else hi = mid; }
    int s = lo;
    lo = 0; hi = n;
    int g1 = g + 1;
    while (lo < hi) { int mid = (lo + hi) >> 1; if (batch[mid] < g1) lo = mid + 1; else hi = mid; }
    cntb[g] = (float)(lo - s);
}

__global__ void pool_k(const ushort* __restrict__ h, const int* __restrict__ batch,
                       float* __restrict__ outsum, int n) {
    int d = threadIdx.x;  // 0..255
    int n0 = blockIdx.x * 128;
    int n1 = min(n0 + 128, n);
    int gcur = -1;
    float sum = 0.f;
    for (int nn = n0; nn < n1; ++nn) {
        int g = batch[nn];
        float v = bf2f(h[(size_t)nn * 256 + d]);
        if (g != gcur) {
            if (gcur >= 0) atomicAdd(&outsum[gcur * 256 + d], sum);
            gcur = g;
            sum = v;
        } else {
            sum += v;
        }
    }
    if (gcur >= 0) atomicAdd(&outsum[gcur * 256 + d], sum);
}

__global__ void final_k(float* __restrict__ out, const float* __restrict__ cntb) {
    int g = blockIdx.x, d = threadIdx.x;
    out[g * 256 + d] /= fmaxf(cntb[g], 1.0f);
}

extern "C" void kernel_launch(void* const* d_in, const int* in_sizes, int n_in,
                              void* d_out, int out_size, void* d_ws, size_t ws_size,
                              hipStream_t stream) {
    const float* x  = (const float*)d_in[0];
    const int*   ei = (const int*)d_in[1];
    const int*   batch = (const int*)d_in[2];
    const float* W1 = (const float*)d_in[3];
    const float* b1 = (const float*)d_in[4];
    const float* W2 = (const float*)d_in[5];
    const float* b2 = (const float*)d_in[6];
    float* out = (float*)d_out;

    const int N  = in_sizes[2];          // 100000
    const int E  = in_sizes[1] / 2;      // 1600000
    const int* row = ei;
    const int* col = ei + E;

    char* p = (char*)d_ws;
    auto alloc = [&](size_t bytes) {
        char* q = p;
        p += (bytes + 255) & ~(size_t)255;
        return q;
    };
    int*    idg    = (int*)alloc((size_t)N * 4);
    int*    startv = (int*)alloc((size_t)N * 4);
    int*    cursor = (int*)alloc((size_t)N * 4);
    int*    bsum   = (int*)alloc(2048);
    int*    bsumx  = (int*)alloc(2048);
    int*    eidx   = (int*)alloc((size_t)E * 4);
    float*  dinv   = (float*)alloc((size_t)N * 4);
    float*  cntb   = (float*)alloc(1024);
    ushort* W1p    = (ushort*)alloc(16 * 4 * 64 * 8 * 2);       // 64 KB
    ushort* W2p    = (ushort*)alloc(16 * 8 * 64 * 8 * 2);       // 128 KB
    ushort* aggX   = (ushort*)alloc((size_t)N * 128 * 2);       // bf16
    ushort* h1     = (ushort*)alloc((size_t)N * 256 * 2);
    ushort* aggH   = (ushort*)alloc((size_t)N * 256 * 2);
    ushort* h2     = (ushort*)alloc((size_t)N * 256 * 2);

    const int nb  = (N + 255) / 256;
    const int ebl = (E + 255) / 256;

    zero_k<<<nb, 256, 0, stream>>>(idg, N);
    zero_k<<<(out_size + 255) / 256, 256, 0, stream>>>((int*)out, out_size);

    // CSR build + normalization
    count_edges_k<<<ebl, 256, 0, stream>>>(col, idg, E);
    dinv_k<<<nb, 256, 0, stream>>>(idg, dinv, N);
    scan1_k<<<nb, 256, 0, stream>>>(idg, startv, bsum, N);
    scan2_k<<<1, 512, 0, stream>>>(bsum, bsumx, nb);
    scan3_k<<<nb, 256, 0, stream>>>(startv, bsumx, cursor, N);
    fill_k<<<ebl, 256, 0, stream>>>(row, col, startv, cursor, eidx, E);

    // weight packing (tiny)
    packW_k<<<128, 256, 0, stream>>>(W1, W1p, 128);
    packW_k<<<256, 256, 0, stream>>>(W2, W2p, 256);

    // layer 1: agg first (linear reorder), then MFMA transform fused bias+relu
    agg1_k<<<(N + 3) / 4, 256, 0, stream>>>(x, aggX, dinv, startv, idg, eidx, N);
    dim3 g1((N + 63) / 64, 4);
    gemm_mfma_k<128><<<g1, 256, 0, stream>>>(aggX, W1p, b1, h1, N);

    // layer 2
    agg2_k<<<(N + 3) / 4, 256, 0, stream>>>(h1, aggH, dinv, startv, idg, eidx, N);
    gemm_mfma_k<256><<<g1, 256, 0, stream>>>(aggH, W2p, b2, h2, N);

    // pool
    cnt_bounds_k<<<1, 64, 0, stream>>>(batch, cntb, N);
    pool_k<<<(N + 127) / 128, 256, 0, stream>>>(h2, batch, out, N);
    final_k<<<64, 256, 0, stream>>>(out, cntb);
}

// Round 4
// 613.170 us; speedup vs baseline: 2.7306x; 1.0717x over previous
//
#include <hip/hip_runtime.h>

typedef __attribute__((ext_vector_type(8))) short short8;    // 8 bf16 (4 VGPRs)
typedef __attribute__((ext_vector_type(4))) float float4v;   // 4 fp32 acc

__device__ __forceinline__ ushort f2bf(float f) {
    uint u = __float_as_uint(f);
    u += 0x7fffu + ((u >> 16) & 1u);   // round-to-nearest-even
    return (ushort)(u >> 16);
}
__device__ __forceinline__ float bf2f(ushort h) {
    return __uint_as_float((uint)h << 16);
}

// ---------------- zero helper ----------------
__global__ void zero_k(int* __restrict__ p, int n) {
    int i = blockIdx.x * 256 + threadIdx.x;
    if (i < n) p[i] = 0;
}

// ---------------- x fp32 -> bf16 (vectorized) ----------------
__global__ void cvt_k(const float* __restrict__ x, ushort* __restrict__ xb, int n4) {
    int i = blockIdx.x * 256 + threadIdx.x;
    if (i < n4) {
        float4 v = ((const float4*)x)[i];
        ushort4 o;
        o.x = f2bf(v.x); o.y = f2bf(v.y); o.z = f2bf(v.z); o.w = f2bf(v.w);
        ((ushort4*)xb)[i] = o;
    }
}

// ---------------- degree count (in-degree by col) ----------------
__global__ void count_edges_k(const int* __restrict__ col, int* __restrict__ idg, int E) {
    int e = blockIdx.x * 256 + threadIdx.x;
    if (e < E) atomicAdd(&idg[col[e]], 1);
}

__global__ void dinv_k(const int* __restrict__ idg, float* __restrict__ dinv, int n) {
    int i = blockIdx.x * 256 + threadIdx.x;
    if (i < n) dinv[i] = rsqrtf((float)(idg[i] + 1));
}

// ---------------- exclusive scan (3 phases) for CSR offsets ----------------
__global__ void scan1_k(const int* __restrict__ idg, int* __restrict__ excl,
                        int* __restrict__ bsum, int n) {
    __shared__ int s[256];
    int t = threadIdx.x, i = blockIdx.x * 256 + t;
    int v = (i < n) ? idg[i] : 0;
    s[t] = v;
    __syncthreads();
    for (int off = 1; off < 256; off <<= 1) {
        int x = (t >= off) ? s[t - off] : 0;
        __syncthreads();
        s[t] += x;
        __syncthreads();
    }
    if (i < n) excl[i] = s[t] - v;
    if (t == 255) bsum[blockIdx.x] = s[255];
}

__global__ void scan2_k(const int* __restrict__ bsum, int* __restrict__ bsumx, int nb) {
    __shared__ int s[512];
    int t = threadIdx.x;
    int v = (t < nb) ? bsum[t] : 0;
    s[t] = v;
    __syncthreads();
    for (int off = 1; off < 512; off <<= 1) {
        int x = (t >= off) ? s[t - off] : 0;
        __syncthreads();
        s[t] += x;
        __syncthreads();
    }
    if (t < nb) bsumx[t] = s[t] - v;
}

__global__ void scan3_k(int* __restrict__ start, const int* __restrict__ bsumx,
                        int* __restrict__ cursor, int n) {
    int i = blockIdx.x * 256 + threadIdx.x;
    if (i < n) { start[i] += bsumx[blockIdx.x]; cursor[i] = 0; }
}

// fill CSR with (src, edge-weight) pairs: removes dependent dinv load from agg
__global__ void fill_k(const int* __restrict__ row, const int* __restrict__ col,
                       const int* __restrict__ start, int* __restrict__ cursor,
                       const float* __restrict__ dinv, int2* __restrict__ ecsr, int E) {
    int e = blockIdx.x * 256 + threadIdx.x;
    if (e < E) {
        int c = col[e], r = row[e];
        int p = atomicAdd(&cursor[c], 1);
        float w = dinv[r] * dinv[c];
        ecsr[start[c] + p] = make_int2(r, __float_as_int(w));
    }
}

// ---------------- unified aggregate: out[i] = w_self*h[i] + sum_e w_e*h[src_e] ----------------
// bf16 in/out, fp32 accumulate. DPL = ushorts per lane (2 -> 128-dim, 4 -> 256-dim).
// one wave per node; 4-deep unroll for MLP (4 independent edge-rec + row chains).
template <int DPL>
__global__ __launch_bounds__(256) void aggT_k(const ushort* __restrict__ h,
                                              ushort* __restrict__ out,
                                              const float* __restrict__ dinv,
                                              const int* __restrict__ start,
                                              const int* __restrict__ idg,
                                              const int2* __restrict__ ecsr, int n) {
    constexpr int DIM = DPL * 64;
    int w = threadIdx.x >> 6, lane = threadIdx.x & 63;
    int i = blockIdx.x * 4 + w;
    if (i >= n) return;
    float di = dinv[i];
    float sw = di * di;
    float acc[DPL];
    {
        const ushort* sp = h + (size_t)i * DIM + lane * DPL;
#pragma unroll
        for (int d = 0; d < DPL; ++d) acc[d] = bf2f(sp[d]) * sw;
    }
    int s0 = start[i], cnt = idg[i];
    const int2* ep = ecsr + s0;
    int j = 0;
    for (; j + 3 < cnt; j += 4) {
        int2 e0 = ep[j], e1 = ep[j + 1], e2 = ep[j + 2], e3 = ep[j + 3];
        const ushort* p0 = h + (size_t)e0.x * DIM + lane * DPL;
        const ushort* p1 = h + (size_t)e1.x * DIM + lane * DPL;
        const ushort* p2 = h + (size_t)e2.x * DIM + lane * DPL;
        const ushort* p3 = h + (size_t)e3.x * DIM + lane * DPL;
        float w0 = __int_as_float(e0.y), w1 = __int_as_float(e1.y);
        float w2 = __int_as_float(e2.y), w3 = __int_as_float(e3.y);
        ushort v0[DPL], v1[DPL], v2[DPL], v3[DPL];
#pragma unroll
        for (int d = 0; d < DPL; ++d) v0[d] = p0[d];
#pragma unroll
        for (int d = 0; d < DPL; ++d) v1[d] = p1[d];
#pragma unroll
        for (int d = 0; d < DPL; ++d) v2[d] = p2[d];
#pragma unroll
        for (int d = 0; d < DPL; ++d) v3[d] = p3[d];
#pragma unroll
        for (int d = 0; d < DPL; ++d) {
            acc[d] = fmaf(bf2f(v0[d]), w0, acc[d]);
            acc[d] = fmaf(bf2f(v1[d]), w1, acc[d]);
            acc[d] = fmaf(bf2f(v2[d]), w2, acc[d]);
            acc[d] = fmaf(bf2f(v3[d]), w3, acc[d]);
        }
    }
    for (; j < cnt; ++j) {
        int2 e0 = ep[j];
        const ushort* p0 = h + (size_t)e0.x * DIM + lane * DPL;
        float w0 = __int_as_float(e0.y);
#pragma unroll
        for (int d = 0; d < DPL; ++d) acc[d] = fmaf(bf2f(p0[d]), w0, acc[d]);
    }
    ushort o[DPL];
#pragma unroll
    for (int d = 0; d < DPL; ++d) o[d] = f2bf(acc[d]);
    ushort* op = out + (size_t)i * DIM + lane * DPL;
    if (DPL == 2) *(ushort2*)op = *(ushort2*)o;
    else          *(ushort4*)op = *(ushort4*)o;
}

// ---------------- pack W[K x 256] fp32 -> bf16 MFMA B-fragment order ----------------
__global__ void packW_k(const float* __restrict__ W, ushort* __restrict__ Wp, int K) {
    int idx = blockIdx.x * 256 + threadIdx.x;
    int S = K / 32;
    int j = idx & 7;
    int lane = (idx >> 3) & 63;
    int s = (idx >> 9) % S;
    int nt = (idx >> 9) / S;
    int k = 32 * s + (lane >> 4) * 8 + j;
    int c = nt * 16 + (lane & 15);
    Wp[idx] = f2bf(W[k * 256 + c]);
}

// ---------------- MFMA bf16 GEMM: C[M,256] = relu(A[M,K] @ W + b), bf16 out ----------------
template <int K>
__global__ __launch_bounds__(256) void gemm_mfma_k(const ushort* __restrict__ A,
                                                   const ushort* __restrict__ Wp,
                                                   const float* __restrict__ bias,
                                                   ushort* __restrict__ C, int M) {
    constexpr int S = K / 32;
    int tid = threadIdx.x, wv = tid >> 6, lane = tid & 63;
    int quad = lane >> 4, l15 = lane & 15;
    int rowBase = blockIdx.x * 64 + wv * 16;
    int arow = rowBase + l15; if (arow > M - 1) arow = M - 1;   // clamp (stores guarded)
    const ushort* abase = A + (size_t)arow * K + quad * 8;
    short8 af[S];
#pragma unroll
    for (int s = 0; s < S; ++s) af[s] = *(const short8*)(abase + 32 * s);

    int ntg0 = blockIdx.y * 4;
    float4v acc[4];
#pragma unroll
    for (int nt = 0; nt < 4; ++nt) {
        float4v a = {0.f, 0.f, 0.f, 0.f};
        const ushort* wb = Wp + ((size_t)(ntg0 + nt) * S * 64 + lane) * 8;
#pragma unroll
        for (int s = 0; s < S; ++s) {
            short8 bf = *(const short8*)(wb + (size_t)s * 64 * 8);
            a = __builtin_amdgcn_mfma_f32_16x16x32_bf16(af[s], bf, a, 0, 0, 0);
        }
        acc[nt] = a;
    }
#pragma unroll
    for (int nt = 0; nt < 4; ++nt) {
        int col = blockIdx.y * 64 + nt * 16 + l15;
        float b = bias[col];
#pragma unroll
        for (int r = 0; r < 4; ++r) {
            int row = rowBase + quad * 4 + r;
            if (row < M) {
                float v = fmaxf(acc[nt][r] + b, 0.f);
                C[(size_t)row * 256 + col] = f2bf(v);
            }
        }
    }
}

// ---------------- mean pool ----------------
__global__ void cnt_bounds_k(const int* __restrict__ batch, float* __restrict__ cntb,
                             int n) {
    int g = threadIdx.x;  // 0..63
    int lo = 0, hi = n;
    while (lo < hi) { int mid = (lo + hi) >> 1; if (batch[mid] < g) lo = mid + 1; else hi = mid; }
    int s = lo;
    lo = 0; hi = n;
    int g1 = g + 1;
    while (lo < hi) { int mid = (lo + hi) >> 1; if (batch[mid] < g1) lo = mid + 1; else hi = mid; }
    cntb[g] = (float)(lo - s);
}

__global__ void pool_k(const ushort* __restrict__ h, const int* __restrict__ batch,
                       float* __restrict__ outsum, int n) {
    int d = threadIdx.x;  // 0..255
    int n0 = blockIdx.x * 128;
    int n1 = min(n0 + 128, n);
    int gcur = -1;
    float sum = 0.f;
    for (int nn = n0; nn < n1; ++nn) {
        int g = batch[nn];
        float v = bf2f(h[(size_t)nn * 256 + d]);
        if (g != gcur) {
            if (gcur >= 0) atomicAdd(&outsum[gcur * 256 + d], sum);
            gcur = g;
            sum = v;
        } else {
            sum += v;
        }
    }
    if (gcur >= 0) atomicAdd(&outsum[gcur * 256 + d], sum);
}

__global__ void final_k(float* __restrict__ out, const float* __restrict__ cntb) {
    int g = blockIdx.x, d = threadIdx.x;
    out[g * 256 + d] /= fmaxf(cntb[g], 1.0f);
}

extern "C" void kernel_launch(void* const* d_in, const int* in_sizes, int n_in,
                              void* d_out, int out_size, void* d_ws, size_t ws_size,
                              hipStream_t stream) {
    const float* x  = (const float*)d_in[0];
    const int*   ei = (const int*)d_in[1];
    const int*   batch = (const int*)d_in[2];
    const float* W1 = (const float*)d_in[3];
    const float* b1 = (const float*)d_in[4];
    const float* W2 = (const float*)d_in[5];
    const float* b2 = (const float*)d_in[6];
    float* out = (float*)d_out;

    const int N  = in_sizes[2];          // 100000
    const int E  = in_sizes[1] / 2;      // 1600000
    const int* row = ei;
    const int* col = ei + E;

    char* p = (char*)d_ws;
    auto alloc = [&](size_t bytes) {
        char* q = p;
        p += (bytes + 255) & ~(size_t)255;
        return q;
    };
    int*    idg    = (int*)alloc((size_t)N * 4);
    int*    startv = (int*)alloc((size_t)N * 4);
    int*    cursor = (int*)alloc((size_t)N * 4);
    int*    bsum   = (int*)alloc(2048);
    int*    bsumx  = (int*)alloc(2048);
    int2*   ecsr   = (int2*)alloc((size_t)E * 8);
    float*  dinv   = (float*)alloc((size_t)N * 4);
    float*  cntb   = (float*)alloc(1024);
    ushort* W1p    = (ushort*)alloc(16 * 4 * 64 * 8 * 2);       // 64 KB
    ushort* W2p    = (ushort*)alloc(16 * 8 * 64 * 8 * 2);       // 128 KB
    ushort* xb     = (ushort*)alloc((size_t)N * 128 * 2);       // bf16 x
    ushort* aggX   = (ushort*)alloc((size_t)N * 128 * 2);
    ushort* h1     = (ushort*)alloc((size_t)N * 256 * 2);
    ushort* aggH   = (ushort*)alloc((size_t)N * 256 * 2);
    ushort* h2     = (ushort*)alloc((size_t)N * 256 * 2);

    const int nb  = (N + 255) / 256;
    const int ebl = (E + 255) / 256;

    zero_k<<<nb, 256, 0, stream>>>(idg, N);
    zero_k<<<(out_size + 255) / 256, 256, 0, stream>>>((int*)out, out_size);

    // x -> bf16 (gathers read half the bytes)
    cvt_k<<<(N * 32 + 255) / 256, 256, 0, stream>>>(x, xb, N * 32);

    // CSR build + normalization (edge weights precomputed into CSR)
    count_edges_k<<<ebl, 256, 0, stream>>>(col, idg, E);
    dinv_k<<<nb, 256, 0, stream>>>(idg, dinv, N);
    scan1_k<<<nb, 256, 0, stream>>>(idg, startv, bsum, N);
    scan2_k<<<1, 512, 0, stream>>>(bsum, bsumx, nb);
    scan3_k<<<nb, 256, 0, stream>>>(startv, bsumx, cursor, N);
    fill_k<<<ebl, 256, 0, stream>>>(row, col, startv, cursor, dinv, ecsr, E);

    // weight packing (tiny)
    packW_k<<<128, 256, 0, stream>>>(W1, W1p, 128);
    packW_k<<<256, 256, 0, stream>>>(W2, W2p, 256);

    // layer 1: agg first (linear reorder), then MFMA transform fused bias+relu
    aggT_k<2><<<(N + 3) / 4, 256, 0, stream>>>(xb, aggX, dinv, startv, idg, ecsr, N);
    dim3 g1((N + 63) / 64, 4);
    gemm_mfma_k<128><<<g1, 256, 0, stream>>>(aggX, W1p, b1, h1, N);

    // layer 2
    aggT_k<4><<<(N + 3) / 4, 256, 0, stream>>>(h1, aggH, dinv, startv, idg, ecsr, N);
    gemm_mfma_k<256><<<g1, 256, 0, stream>>>(aggH, W2p, b2, h2, N);

    // pool
    cnt_bounds_k<<<1, 64, 0, stream>>>(batch, cntb, N);
    pool_k<<<(N + 127) / 128, 256, 0, stream>>>(h2, batch, out, N);
    final_k<<<64, 256, 0, stream>>>(out, cntb);
}

// Round 5
// 600.443 us; speedup vs baseline: 2.7885x; 1.0212x over previous
//
#include <hip/hip_runtime.h>

typedef __attribute__((ext_vector_type(8))) short short8;    // 8 bf16 (4 VGPRs)
typedef __attribute__((ext_vector_type(4))) float float4v;   // 4 fp32 acc

__device__ __forceinline__ ushort f2bf(float f) {
    uint u = __float_as_uint(f);
    u += 0x7fffu + ((u >> 16) & 1u);   // round-to-nearest-even
    return (ushort)(u >> 16);
}
__device__ __forceinline__ float bf2f(ushort h) {
    return __uint_as_float((uint)h << 16);
}
__device__ __forceinline__ void acc8(float* acc, uint4 v) {
    acc[0] += __uint_as_float(v.x << 16);
    acc[1] += __uint_as_float(v.x & 0xffff0000u);
    acc[2] += __uint_as_float(v.y << 16);
    acc[3] += __uint_as_float(v.y & 0xffff0000u);
    acc[4] += __uint_as_float(v.z << 16);
    acc[5] += __uint_as_float(v.z & 0xffff0000u);
    acc[6] += __uint_as_float(v.w << 16);
    acc[7] += __uint_as_float(v.w & 0xffff0000u);
}

// ---------------- zero helper ----------------
__global__ void zero_k(int* __restrict__ p, int n) {
    int i = blockIdx.x * 256 + threadIdx.x;
    if (i < n) p[i] = 0;
}

// ---------------- x fp32 -> bf16, pre-scaled by dinv[node] ----------------
__global__ void cvt_k(const float* __restrict__ x, const float* __restrict__ dinv,
                      ushort* __restrict__ xb, int n4) {
    int i = blockIdx.x * 256 + threadIdx.x;
    if (i < n4) {
        int node = i >> 5;                 // 32 float4 per 128-dim row
        float di = dinv[node];
        float4 v = ((const float4*)x)[i];
        ushort4 o;
        o.x = f2bf(v.x * di); o.y = f2bf(v.y * di);
        o.z = f2bf(v.z * di); o.w = f2bf(v.w * di);
        ((ushort4*)xb)[i] = o;
    }
}

// ---------------- degree count (in-degree by col) ----------------
__global__ void count_edges_k(const int* __restrict__ col, int* __restrict__ idg, int E) {
    int e = blockIdx.x * 256 + threadIdx.x;
    if (e < E) atomicAdd(&idg[col[e]], 1);
}

__global__ void dinv_k(const int* __restrict__ idg, float* __restrict__ dinv, int n) {
    int i = blockIdx.x * 256 + threadIdx.x;
    if (i < n) dinv[i] = rsqrtf((float)(idg[i] + 1));
}

// ---------------- exclusive scan (3 phases) for CSR offsets ----------------
__global__ void scan1_k(const int* __restrict__ idg, int* __restrict__ excl,
                        int* __restrict__ bsum, int n) {
    __shared__ int s[256];
    int t = threadIdx.x, i = blockIdx.x * 256 + t;
    int v = (i < n) ? idg[i] : 0;
    s[t] = v;
    __syncthreads();
    for (int off = 1; off < 256; off <<= 1) {
        int x = (t >= off) ? s[t - off] : 0;
        __syncthreads();
        s[t] += x;
        __syncthreads();
    }
    if (i < n) excl[i] = s[t] - v;
    if (t == 255) bsum[blockIdx.x] = s[255];
}

__global__ void scan2_k(const int* __restrict__ bsum, int* __restrict__ bsumx, int nb) {
    __shared__ int s[512];
    int t = threadIdx.x;
    int v = (t < nb) ? bsum[t] : 0;
    s[t] = v;
    __syncthreads();
    for (int off = 1; off < 512; off <<= 1) {
        int x = (t >= off) ? s[t - off] : 0;
        __syncthreads();
        s[t] += x;
        __syncthreads();
    }
    if (t < nb) bsumx[t] = s[t] - v;
}

__global__ void scan3_k(int* __restrict__ start, const int* __restrict__ bsumx,
                        int* __restrict__ cursor, int n) {
    int i = blockIdx.x * 256 + threadIdx.x;
    if (i < n) { start[i] += bsumx[blockIdx.x]; cursor[i] = 0; }
}

// fill CSR: 4-B src-index records (weights folded into features)
__global__ void fill_k(const int* __restrict__ row, const int* __restrict__ col,
                       const int* __restrict__ start, int* __restrict__ cursor,
                       int* __restrict__ eidx, int E) {
    int e = blockIdx.x * 256 + threadIdx.x;
    if (e < E) {
        int c = col[e];
        int p = atomicAdd(&cursor[c], 1);
        eidx[start[c] + p] = row[e];
    }
}

// ---------------- agg, 128-dim rows (256 B): out[i] = dinv[i]*(g[i] + sum g[src]) ----------------
// 4 edges per wave-iteration: 16 lanes x 16 B each; unroll x2 (8 edges in flight)
__global__ __launch_bounds__(256) void agg128_k(const ushort* __restrict__ g,
                                                ushort* __restrict__ out,
                                                const float* __restrict__ dinv,
                                                const int* __restrict__ start,
                                                const int* __restrict__ idg,
                                                const int* __restrict__ eidx, int n) {
    int w = threadIdx.x >> 6, lane = threadIdx.x & 63;
    int i = blockIdx.x * 4 + w;
    if (i >= n) return;
    int q = lane >> 4, sub = lane & 15;          // quarter, 16-B chunk id
    float acc[8] = {};
    if (q == 0) {  // self term once
        uint4 v = *(const uint4*)(g + (size_t)i * 128 + sub * 8);
        acc8(acc, v);
    }
    int s0 = start[i], cnt = idg[i];
    int j = q;
    for (; j + 4 < cnt; j += 8) {
        int sA = eidx[s0 + j], sB = eidx[s0 + j + 4];
        uint4 vA = *(const uint4*)(g + (size_t)sA * 128 + sub * 8);
        uint4 vB = *(const uint4*)(g + (size_t)sB * 128 + sub * 8);
        acc8(acc, vA);
        acc8(acc, vB);
    }
    for (; j < cnt; j += 4) {
        int sA = eidx[s0 + j];
        uint4 vA = *(const uint4*)(g + (size_t)sA * 128 + sub * 8);
        acc8(acc, vA);
    }
#pragma unroll
    for (int d = 0; d < 8; ++d) {
        acc[d] += __shfl_xor(acc[d], 16);
        acc[d] += __shfl_xor(acc[d], 32);
    }
    if (q == 0) {
        float di = dinv[i];
        uint4 o;
        o.x = (uint)f2bf(acc[0] * di) | ((uint)f2bf(acc[1] * di) << 16);
        o.y = (uint)f2bf(acc[2] * di) | ((uint)f2bf(acc[3] * di) << 16);
        o.z = (uint)f2bf(acc[4] * di) | ((uint)f2bf(acc[5] * di) << 16);
        o.w = (uint)f2bf(acc[6] * di) | ((uint)f2bf(acc[7] * di) << 16);
        *(uint4*)(out + (size_t)i * 128 + sub * 8) = o;
    }
}

// ---------------- agg, 256-dim rows (512 B) ----------------
// 2 edges per wave-iteration: 32 lanes x 16 B each; unroll x2 (4 edges in flight)
__global__ __launch_bounds__(256) void agg256_k(const ushort* __restrict__ g,
                                                ushort* __restrict__ out,
                                                const float* __restrict__ dinv,
                                                const int* __restrict__ start,
                                                const int* __restrict__ idg,
                                                const int* __restrict__ eidx, int n) {
    int w = threadIdx.x >> 6, lane = threadIdx.x & 63;
    int i = blockIdx.x * 4 + w;
    if (i >= n) return;
    int half = lane >> 5, sub = lane & 31;
    float acc[8] = {};
    if (half == 0) {
        uint4 v = *(const uint4*)(g + (size_t)i * 256 + sub * 8);
        acc8(acc, v);
    }
    int s0 = start[i], cnt = idg[i];
    int j = half;
    for (; j + 2 < cnt; j += 4) {
        int sA = eidx[s0 + j], sB = eidx[s0 + j + 2];
        uint4 vA = *(const uint4*)(g + (size_t)sA * 256 + sub * 8);
        uint4 vB = *(const uint4*)(g + (size_t)sB * 256 + sub * 8);
        acc8(acc, vA);
        acc8(acc, vB);
    }
    for (; j < cnt; j += 2) {
        int sA = eidx[s0 + j];
        uint4 vA = *(const uint4*)(g + (size_t)sA * 256 + sub * 8);
        acc8(acc, vA);
    }
#pragma unroll
    for (int d = 0; d < 8; ++d) acc[d] += __shfl_xor(acc[d], 32);
    if (half == 0) {
        float di = dinv[i];
        uint4 o;
        o.x = (uint)f2bf(acc[0] * di) | ((uint)f2bf(acc[1] * di) << 16);
        o.y = (uint)f2bf(acc[2] * di) | ((uint)f2bf(acc[3] * di) << 16);
        o.z = (uint)f2bf(acc[4] * di) | ((uint)f2bf(acc[5] * di) << 16);
        o.w = (uint)f2bf(acc[6] * di) | ((uint)f2bf(acc[7] * di) << 16);
        *(uint4*)(out + (size_t)i * 256 + sub * 8) = o;
    }
}

// ---------------- pack W[K x 256] fp32 -> bf16 MFMA B-fragment order ----------------
__global__ void packW_k(const float* __restrict__ W, ushort* __restrict__ Wp, int K) {
    int idx = blockIdx.x * 256 + threadIdx.x;
    int S = K / 32;
    int j = idx & 7;
    int lane = (idx >> 3) & 63;
    int s = (idx >> 9) % S;
    int nt = (idx >> 9) / S;
    int k = 32 * s + (lane >> 4) * 8 + j;
    int c = nt * 16 + (lane & 15);
    Wp[idx] = f2bf(W[k * 256 + c]);
}

// ---------------- MFMA bf16 GEMM: C[M,256] = relu(A[M,K] @ W + b) [*dinv[row] if SCALE] ----------------
template <int K, bool SCALE>
__global__ __launch_bounds__(256) void gemm_mfma_k(const ushort* __restrict__ A,
                                                   const ushort* __restrict__ Wp,
                                                   const float* __restrict__ bias,
                                                   const float* __restrict__ dinv,
                                                   ushort* __restrict__ C, int M) {
    constexpr int S = K / 32;
    int tid = threadIdx.x, wv = tid >> 6, lane = tid & 63;
    int quad = lane >> 4, l15 = lane & 15;
    int rowBase = blockIdx.x * 64 + wv * 16;
    int arow = rowBase + l15; if (arow > M - 1) arow = M - 1;   // clamp (stores guarded)
    const ushort* abase = A + (size_t)arow * K + quad * 8;
    short8 af[S];
#pragma unroll
    for (int s = 0; s < S; ++s) af[s] = *(const short8*)(abase + 32 * s);

    int ntg0 = blockIdx.y * 4;
    float4v acc[4];
#pragma unroll
    for (int nt = 0; nt < 4; ++nt) {
        float4v a = {0.f, 0.f, 0.f, 0.f};
        const ushort* wb = Wp + ((size_t)(ntg0 + nt) * S * 64 + lane) * 8;
#pragma unroll
        for (int s = 0; s < S; ++s) {
            short8 bf = *(const short8*)(wb + (size_t)s * 64 * 8);
            a = __builtin_amdgcn_mfma_f32_16x16x32_bf16(af[s], bf, a, 0, 0, 0);
        }
        acc[nt] = a;
    }
#pragma unroll
    for (int nt = 0; nt < 4; ++nt) {
        int col = blockIdx.y * 64 + nt * 16 + l15;
        float b = bias[col];
#pragma unroll
        for (int r = 0; r < 4; ++r) {
            int row = rowBase + quad * 4 + r;
            if (row < M) {
                float v = fmaxf(acc[nt][r] + b, 0.f);
                if (SCALE) v *= dinv[row];
                C[(size_t)row * 256 + col] = f2bf(v);
            }
        }
    }
}

// ---------------- mean pool ----------------
__global__ void cnt_bounds_k(const int* __restrict__ batch, float* __restrict__ cntb,
                             int n) {
    int g = threadIdx.x;  // 0..63
    int lo = 0, hi = n;
    while (lo < hi) { int mid = (lo + hi) >> 1; if (batch[mid] < g) lo = mid + 1; else hi = mid; }
    int s = lo;
    lo = 0; hi = n;
    int g1 = g + 1;
    while (lo < hi) { int mid = (lo + hi) >> 1; if (batch[mid] < g1) lo = mid + 1; else hi = mid; }
    cntb[g] = (float)(lo - s);
}

__global__ void pool_k(const ushort* __restrict__ h, const int* __restrict__ batch,
                       float* __restrict__ outsum, int n) {
    int d = threadIdx.x;  // 0..255
    int n0 = blockIdx.x * 128;
    int n1 = min(n0 + 128, n);
    int gcur = -1;
    float sum = 0.f;
    for (int nn = n0; nn < n1; ++nn) {
        int g = batch[nn];
        float v = bf2f(h[(size_t)nn * 256 + d]);
        if (g != gcur) {
            if (gcur >= 0) atomicAdd(&outsum[gcur * 256 + d], sum);
            gcur = g;
            sum = v;
        } else {
            sum += v;
        }
    }
    if (gcur >= 0) atomicAdd(&outsum[gcur * 256 + d], sum);
}

__global__ void final_k(float* __restrict__ out, const float* __restrict__ cntb) {
    int g = blockIdx.x, d = threadIdx.x;
    out[g * 256 + d] /= fmaxf(cntb[g], 1.0f);
}

extern "C" void kernel_launch(void* const* d_in, const int* in_sizes, int n_in,
                              void* d_out, int out_size, void* d_ws, size_t ws_size,
                              hipStream_t stream) {
    const float* x  = (const float*)d_in[0];
    const int*   ei = (const int*)d_in[1];
    const int*   batch = (const int*)d_in[2];
    const float* W1 = (const float*)d_in[3];
    const float* b1 = (const float*)d_in[4];
    const float* W2 = (const float*)d_in[5];
    const float* b2 = (const float*)d_in[6];
    float* out = (float*)d_out;

    const int N  = in_sizes[2];          // 100000
    const int E  = in_sizes[1] / 2;      // 1600000
    const int* row = ei;
    const int* col = ei + E;

    char* p = (char*)d_ws;
    auto alloc = [&](size_t bytes) {
        char* q = p;
        p += (bytes + 255) & ~(size_t)255;
        return q;
    };
    int*    idg    = (int*)alloc((size_t)N * 4);
    int*    startv = (int*)alloc((size_t)N * 4);
    int*    cursor = (int*)alloc((size_t)N * 4);
    int*    bsum   = (int*)alloc(2048);
    int*    bsumx  = (int*)alloc(2048);
    int*    eidx   = (int*)alloc((size_t)E * 4);
    float*  dinv   = (float*)alloc((size_t)N * 4);
    float*  cntb   = (float*)alloc(1024);
    ushort* W1p    = (ushort*)alloc(16 * 4 * 64 * 8 * 2);       // 64 KB
    ushort* W2p    = (ushort*)alloc(16 * 8 * 64 * 8 * 2);       // 128 KB
    ushort* xb     = (ushort*)alloc((size_t)N * 128 * 2);       // bf16 dinv*x
    ushort* aggX   = (ushort*)alloc((size_t)N * 128 * 2);
    ushort* g1     = (ushort*)alloc((size_t)N * 256 * 2);       // dinv*h1
    ushort* aggH   = (ushort*)alloc((size_t)N * 256 * 2);
    ushort* h2     = (ushort*)alloc((size_t)N * 256 * 2);

    const int nb  = (N + 255) / 256;
    const int ebl = (E + 255) / 256;

    zero_k<<<nb, 256, 0, stream>>>(idg, N);
    zero_k<<<(out_size + 255) / 256, 256, 0, stream>>>((int*)out, out_size);

    // CSR build + normalization (plain src-index records)
    count_edges_k<<<ebl, 256, 0, stream>>>(col, idg, E);
    dinv_k<<<nb, 256, 0, stream>>>(idg, dinv, N);
    scan1_k<<<nb, 256, 0, stream>>>(idg, startv, bsum, N);
    scan2_k<<<1, 512, 0, stream>>>(bsum, bsumx, nb);
    scan3_k<<<nb, 256, 0, stream>>>(startv, bsumx, cursor, N);
    fill_k<<<ebl, 256, 0, stream>>>(row, col, startv, cursor, eidx, E);

    // x -> bf16 pre-scaled by dinv (after dinv_k)
    cvt_k<<<(N * 32 + 255) / 256, 256, 0, stream>>>(x, dinv, xb, N * 32);

    // weight packing (tiny)
    packW_k<<<128, 256, 0, stream>>>(W1, W1p, 128);
    packW_k<<<256, 256, 0, stream>>>(W2, W2p, 256);

    // layer 1: agg first (linear reorder), then MFMA transform; epilogue scales by dinv
    agg128_k<<<(N + 3) / 4, 256, 0, stream>>>(xb, aggX, dinv, startv, idg, eidx, N);
    dim3 gg((N + 63) / 64, 4);
    gemm_mfma_k<128, true><<<gg, 256, 0, stream>>>(aggX, W1p, b1, dinv, g1, N);

    // layer 2
    agg256_k<<<(N + 3) / 4, 256, 0, stream>>>(g1, aggH, dinv, startv, idg, eidx, N);
    gemm_mfma_k<256, false><<<gg, 256, 0, stream>>>(aggH, W2p, b2, nullptr, h2, N);

    // pool
    cnt_bounds_k<<<1, 64, 0, stream>>>(batch, cntb, N);
    pool_k<<<(N + 127) / 128, 256, 0, stream>>>(h2, batch, out, N);
    final_k<<<64, 256, 0, stream>>>(out, cntb);
}

// Round 7
// 598.059 us; speedup vs baseline: 2.7996x; 1.0040x over previous
//
#include <hip/hip_runtime.h>

typedef __attribute__((ext_vector_type(8))) short short8;    // 8 bf16 (4 VGPRs)
typedef __attribute__((ext_vector_type(4))) float float4v;   // 4 fp32 acc

__device__ __forceinline__ ushort f2bf(float f) {
    uint u = __float_as_uint(f);
    u += 0x7fffu + ((u >> 16) & 1u);   // round-to-nearest-even
    return (ushort)(u >> 16);
}
__device__ __forceinline__ float bf2f(ushort h) {
    return __uint_as_float((uint)h << 16);
}
__device__ __forceinline__ void acc8(float* acc, uint4 v) {
    acc[0] += __uint_as_float(v.x << 16);
    acc[1] += __uint_as_float(v.x & 0xffff0000u);
    acc[2] += __uint_as_float(v.y << 16);
    acc[3] += __uint_as_float(v.y & 0xffff0000u);
    acc[4] += __uint_as_float(v.z << 16);
    acc[5] += __uint_as_float(v.z & 0xffff0000u);
    acc[6] += __uint_as_float(v.w << 16);
    acc[7] += __uint_as_float(v.w & 0xffff0000u);
}
// defensive clamp: garbage index can never fault (1 VALU op vs ~500-cyc gather)
__device__ __forceinline__ int clampi(int v, int n) {
    return (int)min((uint)v, (uint)(n - 1));
}

// ---------------- zero helper ----------------
__global__ void zero_k(int* __restrict__ p, int n) {
    int i = blockIdx.x * 256 + threadIdx.x;
    if (i < n) p[i] = 0;
}

// ---------------- x fp32 -> bf16, pre-scaled by dinv[node] ----------------
__global__ void cvt_k(const float* __restrict__ x, const float* __restrict__ dinv,
                      ushort* __restrict__ xb, int n4) {
    int i = blockIdx.x * 256 + threadIdx.x;
    if (i < n4) {
        int node = i >> 5;                 // 32 float4 per 128-dim row
        float di = dinv[node];
        float4 v = ((const float4*)x)[i];
        ushort4 o;
        o.x = f2bf(v.x * di); o.y = f2bf(v.y * di);
        o.z = f2bf(v.z * di); o.w = f2bf(v.w * di);
        ((ushort4*)xb)[i] = o;
    }
}

// ---------------- degree count (in-degree by col) ----------------
__global__ void count_edges_k(const int* __restrict__ col, int* __restrict__ idg, int E) {
    int e = blockIdx.x * 256 + threadIdx.x;
    if (e < E) atomicAdd(&idg[col[e]], 1);
}

// ---------------- exclusive scan (3 phases) + dinv fused into phase 1 ----------------
__global__ void scan1_k(const int* __restrict__ idg, int* __restrict__ excl,
                        int* __restrict__ bsum, float* __restrict__ dinv, int n) {
    __shared__ int s[256];
    int t = threadIdx.x, i = blockIdx.x * 256 + t;
    int v = (i < n) ? idg[i] : 0;
    if (i < n) dinv[i] = rsqrtf((float)(v + 1));
    s[t] = v;
    __syncthreads();
    for (int off = 1; off < 256; off <<= 1) {
        int x = (t >= off) ? s[t - off] : 0;
        __syncthreads();
        s[t] += x;
        __syncthreads();
    }
    if (i < n) excl[i] = s[t] - v;
    if (t == 255) bsum[blockIdx.x] = s[255];
}

__global__ void scan2_k(const int* __restrict__ bsum, int* __restrict__ bsumx, int nb) {
    __shared__ int s[512];
    int t = threadIdx.x;
    int v = (t < nb) ? bsum[t] : 0;
    s[t] = v;
    __syncthreads();
    for (int off = 1; off < 512; off <<= 1) {
        int x = (t >= off) ? s[t - off] : 0;
        __syncthreads();
        s[t] += x;
        __syncthreads();
    }
    if (t < nb) bsumx[t] = s[t] - v;
}

__global__ void scan3_k(int* __restrict__ start, const int* __restrict__ bsumx,
                        int* __restrict__ cursor, int n) {
    int i = blockIdx.x * 256 + threadIdx.x;
    if (i < n) { start[i] += bsumx[blockIdx.x]; cursor[i] = 0; }
}

// fill CSR: 4-B src-index records (weights folded into features)
__global__ void fill_k(const int* __restrict__ row, const int* __restrict__ col,
                       const int* __restrict__ start, int* __restrict__ cursor,
                       int* __restrict__ eidx, int E) {
    int e = blockIdx.x * 256 + threadIdx.x;
    if (e < E) {
        int c = col[e];
        int p = atomicAdd(&cursor[c], 1);
        eidx[start[c] + p] = row[e];
    }
}

// ---------------- agg, 128-dim rows (256 B): out[i] = dinv[i]*(g[i] + sum g[src]) ----------------
// 4 edges per wave-iteration (16 lanes x 16 B); unroll x4 -> 16 edges / 4 loads in flight
__global__ __launch_bounds__(256) void agg128_k(const ushort* __restrict__ g,
                                                ushort* __restrict__ out,
                                                const float* __restrict__ dinv,
                                                const int* __restrict__ start,
                                                const int* __restrict__ idg,
                                                const int* __restrict__ eidx, int n) {
    int w = threadIdx.x >> 6, lane = threadIdx.x & 63;
    int i = blockIdx.x * 4 + w;
    if (i >= n) return;
    int q = lane >> 4, sub = lane & 15;          // quarter, 16-B chunk id
    float acc[8] = {};
    if (q == 0) {  // self term once
        uint4 v = *(const uint4*)(g + (size_t)i * 128 + sub * 8);
        acc8(acc, v);
    }
    int s0 = start[i], cnt = idg[i];
    int j = q;
    for (; j + 12 < cnt; j += 16) {
        int sA = clampi(eidx[s0 + j], n),     sB = clampi(eidx[s0 + j + 4], n);
        int sC = clampi(eidx[s0 + j + 8], n), sD = clampi(eidx[s0 + j + 12], n);
        uint4 vA = *(const uint4*)(g + (size_t)sA * 128 + sub * 8);
        uint4 vB = *(const uint4*)(g + (size_t)sB * 128 + sub * 8);
        uint4 vC = *(const uint4*)(g + (size_t)sC * 128 + sub * 8);
        uint4 vD = *(const uint4*)(g + (size_t)sD * 128 + sub * 8);
        acc8(acc, vA);
        acc8(acc, vB);
        acc8(acc, vC);
        acc8(acc, vD);
    }
    for (; j < cnt; j += 4) {
        int sA = clampi(eidx[s0 + j], n);
        uint4 vA = *(const uint4*)(g + (size_t)sA * 128 + sub * 8);
        acc8(acc, vA);
    }
#pragma unroll
    for (int d = 0; d < 8; ++d) {
        acc[d] += __shfl_xor(acc[d], 16);
        acc[d] += __shfl_xor(acc[d], 32);
    }
    if (q == 0) {
        float di = dinv[i];
        uint4 o;
        o.x = (uint)f2bf(acc[0] * di) | ((uint)f2bf(acc[1] * di) << 16);
        o.y = (uint)f2bf(acc[2] * di) | ((uint)f2bf(acc[3] * di) << 16);
        o.z = (uint)f2bf(acc[4] * di) | ((uint)f2bf(acc[5] * di) << 16);
        o.w = (uint)f2bf(acc[6] * di) | ((uint)f2bf(acc[7] * di) << 16);
        *(uint4*)(out + (size_t)i * 128 + sub * 8) = o;
    }
}

// ---------------- agg, 256-dim rows (512 B) ----------------
// 2 edges per wave-iteration (32 lanes x 16 B); unroll x4 -> 8 edges / 4 loads in flight
__global__ __launch_bounds__(256) void agg256_k(const ushort* __restrict__ g,
                                                ushort* __restrict__ out,
                                                const float* __restrict__ dinv,
                                                const int* __restrict__ start,
                                                const int* __restrict__ idg,
                                                const int* __restrict__ eidx, int n) {
    int w = threadIdx.x >> 6, lane = threadIdx.x & 63;
    int i = blockIdx.x * 4 + w;
    if (i >= n) return;
    int half = lane >> 5, sub = lane & 31;
    float acc[8] = {};
    if (half == 0) {
        uint4 v = *(const uint4*)(g + (size_t)i * 256 + sub * 8);
        acc8(acc, v);
    }
    int s0 = start[i], cnt = idg[i];
    int j = half;
    for (; j + 6 < cnt; j += 8) {
        int sA = clampi(eidx[s0 + j], n),     sB = clampi(eidx[s0 + j + 2], n);
        int sC = clampi(eidx[s0 + j + 4], n), sD = clampi(eidx[s0 + j + 6], n);
        uint4 vA = *(const uint4*)(g + (size_t)sA * 256 + sub * 8);
        uint4 vB = *(const uint4*)(g + (size_t)sB * 256 + sub * 8);
        uint4 vC = *(const uint4*)(g + (size_t)sC * 256 + sub * 8);
        uint4 vD = *(const uint4*)(g + (size_t)sD * 256 + sub * 8);
        acc8(acc, vA);
        acc8(acc, vB);
        acc8(acc, vC);
        acc8(acc, vD);
    }
    for (; j < cnt; j += 2) {
        int sA = clampi(eidx[s0 + j], n);
        uint4 vA = *(const uint4*)(g + (size_t)sA * 256 + sub * 8);
        acc8(acc, vA);
    }
#pragma unroll
    for (int d = 0; d < 8; ++d) acc[d] += __shfl_xor(acc[d], 32);
    if (half == 0) {
        float di = dinv[i];
        uint4 o;
        o.x = (uint)f2bf(acc[0] * di) | ((uint)f2bf(acc[1] * di) << 16);
        o.y = (uint)f2bf(acc[2] * di) | ((uint)f2bf(acc[3] * di) << 16);
        o.z = (uint)f2bf(acc[4] * di) | ((uint)f2bf(acc[5] * di) << 16);
        o.w = (uint)f2bf(acc[6] * di) | ((uint)f2bf(acc[7] * di) << 16);
        *(uint4*)(out + (size_t)i * 256 + sub * 8) = o;
    }
}

// ---------------- pack W[K x 256] fp32 -> bf16 MFMA B-fragment order ----------------
__global__ void packW_k(const float* __restrict__ W, ushort* __restrict__ Wp, int K) {
    int idx = blockIdx.x * 256 + threadIdx.x;
    int S = K / 32;
    int j = idx & 7;
    int lane = (idx >> 3) & 63;
    int s = (idx >> 9) % S;
    int nt = (idx >> 9) / S;
    int k = 32 * s + (lane >> 4) * 8 + j;
    int c = nt * 16 + (lane & 15);
    Wp[idx] = f2bf(W[k * 256 + c]);
}

// ---------------- MFMA bf16 GEMM: C[M,256] = relu(A[M,K] @ W + b) [*dinv[row] if SCALE] ----------------
template <int K, bool SCALE>
__global__ __launch_bounds__(256) void gemm_mfma_k(const ushort* __restrict__ A,
                                                   const ushort* __restrict__ Wp,
                                                   const float* __restrict__ bias,
                                                   const float* __restrict__ dinv,
                                                   ushort* __restrict__ C, int M) {
    constexpr int S = K / 32;
    int tid = threadIdx.x, wv = tid >> 6, lane = tid & 63;
    int quad = lane >> 4, l15 = lane & 15;
    int rowBase = blockIdx.x * 64 + wv * 16;
    int arow = rowBase + l15; if (arow > M - 1) arow = M - 1;   // clamp (stores guarded)
    const ushort* abase = A + (size_t)arow * K + quad * 8;
    short8 af[S];
#pragma unroll
    for (int s = 0; s < S; ++s) af[s] = *(const short8*)(abase + 32 * s);

    int ntg0 = blockIdx.y * 4;
    float4v acc[4];
#pragma unroll
    for (int nt = 0; nt < 4; ++nt) {
        float4v a = {0.f, 0.f, 0.f, 0.f};
        const ushort* wb = Wp + ((size_t)(ntg0 + nt) * S * 64 + lane) * 8;
#pragma unroll
        for (int s = 0; s < S; ++s) {
            short8 bf = *(const short8*)(wb + (size_t)s * 64 * 8);
            a = __builtin_amdgcn_mfma_f32_16x16x32_bf16(af[s], bf, a, 0, 0, 0);
        }
        acc[nt] = a;
    }
#pragma unroll
    for (int nt = 0; nt < 4; ++nt) {
        int col = blockIdx.y * 64 + nt * 16 + l15;
        float b = bias[col];
#pragma unroll
        for (int r = 0; r < 4; ++r) {
            int row = rowBase + quad * 4 + r;
            if (row < M) {
                float v = fmaxf(acc[nt][r] + b, 0.f);
                if (SCALE) v *= dinv[row];
                C[(size_t)row * 256 + col] = f2bf(v);
            }
        }
    }
}

// ---------------- mean pool ----------------
__global__ void cnt_bounds_k(const int* __restrict__ batch, float* __restrict__ cntb,
                             int n) {
    int g = threadIdx.x;  // 0..63
    int lo = 0, hi = n;
    while (lo < hi) { int mid = (lo + hi) >> 1; if (batch[mid] < g) lo = mid + 1; else hi = mid; }
    int s = lo;
    lo = 0; hi = n;
    int g1 = g + 1;
    while (lo < hi) { int mid = (lo + hi) >> 1; if (batch[mid] < g1) lo = mid + 1; else hi = mid; }
    cntb[g] = (float)(lo - s);
}

__global__ void pool_k(const ushort* __restrict__ h, const int* __restrict__ batch,
                       float* __restrict__ outsum, int n) {
    int d = threadIdx.x;  // 0..255
    int n0 = blockIdx.x * 128;
    int n1 = min(n0 + 128, n);
    int gcur = -1;
    float sum = 0.f;
    for (int nn = n0; nn < n1; ++nn) {
        int g = batch[nn] & 63;
        float v = bf2f(h[(size_t)nn * 256 + d]);
        if (g != gcur) {
            if (gcur >= 0) atomicAdd(&outsum[gcur * 256 + d], sum);
            gcur = g;
            sum = v;
        } else {
            sum += v;
        }
    }
    if (gcur >= 0) atomicAdd(&outsum[gcur * 256 + d], sum);
}

__global__ void final_k(float* __restrict__ out, const float* __restrict__ cntb) {
    int g = blockIdx.x, d = threadIdx.x;
    out[g * 256 + d] /= fmaxf(cntb[g], 1.0f);
}

extern "C" void kernel_launch(void* const* d_in, const int* in_sizes, int n_in,
                              void* d_out, int out_size, void* d_ws, size_t ws_size,
                              hipStream_t stream) {
    const float* x  = (const float*)d_in[0];
    const int*   ei = (const int*)d_in[1];
    const int*   batch = (const int*)d_in[2];
    const float* W1 = (const float*)d_in[3];
    const float* b1 = (const float*)d_in[4];
    const float* W2 = (const float*)d_in[5];
    const float* b2 = (const float*)d_in[6];
    float* out = (float*)d_out;

    const int N  = in_sizes[2];          // 100000
    const int E  = in_sizes[1] / 2;      // 1600000
    const int* row = ei;
    const int* col = ei + E;

    char* p = (char*)d_ws;
    auto alloc = [&](size_t bytes) {
        char* q = p;
        p += (bytes + 255) & ~(size_t)255;
        return q;
    };
    int*    idg    = (int*)alloc((size_t)N * 4);
    int*    startv = (int*)alloc((size_t)N * 4);
    int*    cursor = (int*)alloc((size_t)N * 4);
    int*    bsum   = (int*)alloc(2048);
    int*    bsumx  = (int*)alloc(2048);
    int*    eidx   = (int*)alloc((size_t)E * 4);
    float*  dinv   = (float*)alloc((size_t)N * 4);
    float*  cntb   = (float*)alloc(1024);
    ushort* W1p    = (ushort*)alloc(16 * 4 * 64 * 8 * 2);       // 64 KB
    ushort* W2p    = (ushort*)alloc(16 * 8 * 64 * 8 * 2);       // 128 KB
    ushort* xb     = (ushort*)alloc((size_t)N * 128 * 2);       // bf16 dinv*x
    ushort* aggX   = (ushort*)alloc((size_t)N * 128 * 2);
    ushort* g1     = (ushort*)alloc((size_t)N * 256 * 2);       // dinv*h1
    ushort* aggH   = (ushort*)alloc((size_t)N * 256 * 2);
    ushort* h2     = (ushort*)alloc((size_t)N * 256 * 2);

    const int nb  = (N + 255) / 256;
    const int ebl = (E + 255) / 256;

    zero_k<<<nb, 256, 0, stream>>>(idg, N);
    zero_k<<<(out_size + 255) / 256, 256, 0, stream>>>((int*)out, out_size);

    // CSR build + normalization (dinv fused into scan1)
    count_edges_k<<<ebl, 256, 0, stream>>>(col, idg, E);
    scan1_k<<<nb, 256, 0, stream>>>(idg, startv, bsum, dinv, N);
    scan2_k<<<1, 512, 0, stream>>>(bsum, bsumx, nb);
    scan3_k<<<nb, 256, 0, stream>>>(startv, bsumx, cursor, N);
    fill_k<<<ebl, 256, 0, stream>>>(row, col, startv, cursor, eidx, E);

    // x -> bf16 pre-scaled by dinv
    cvt_k<<<(N * 32 + 255) / 256, 256, 0, stream>>>(x, dinv, xb, N * 32);

    // weight packing (tiny)
    packW_k<<<128, 256, 0, stream>>>(W1, W1p, 128);
    packW_k<<<256, 256, 0, stream>>>(W2, W2p, 256);

    // layer 1: agg first (linear reorder), then MFMA transform; epilogue scales by dinv
    agg128_k<<<(N + 3) / 4, 256, 0, stream>>>(xb, aggX, dinv, startv, idg, eidx, N);
    dim3 gg((N + 63) / 64, 4);
    gemm_mfma_k<128, true><<<gg, 256, 0, stream>>>(aggX, W1p, b1, dinv, g1, N);

    // layer 2
    agg256_k<<<(N + 3) / 4, 256, 0, stream>>>(g1, aggH, dinv, startv, idg, eidx, N);
    gemm_mfma_k<256, false><<<gg, 256, 0, stream>>>(aggH, W2p, b2, nullptr, h2, N);

    // pool
    cnt_bounds_k<<<1, 64, 0, stream>>>(batch, cntb, N);
    pool_k<<<(N + 127) / 128, 256, 0, stream>>>(h2, batch, out, N);
    final_k<<<64, 256, 0, stream>>>(out, cntb);
}